// Round 3
// baseline (8193.088 us; speedup 1.0000x reference)
//
#include <hip/hip_runtime.h>

// ---------------------------------------------------------------------------
// BiLSTM (T=512, B=128, D_IN=400, H=400, L=2) on gfx950.
// Phase A: xg = X @ [Wf;Wb]^T + bias  (fp16 MFMA GEMM, gate-interleaved cols,
//          fp16 output).  fp16 (not bf16): 4x finer eps, same MFMA rate.
// Phase B: recurrence distributed over 5 blocks per (dir, 16-row batch chunk);
//          w_hh in registers (260 VGPR/wave), h exchanged through L3 with
//          agent-scope atomics + flag handshake. 80 blocks, all co-resident.
// ---------------------------------------------------------------------------

#define TT 512
#define BB 128
#define DIN 400
#define HH 400
#define MM (TT * BB)       // 65536
#define NGEMM 3200         // 2 dirs x 1600 gate cols (interleaved (unit,gate))
#define KP0 448            // 400 padded to mult of 64
#define KP1 832            // 800 padded to mult of 64
#define NFRAG 100          // 1600/16 col fragments per dir
#define KFH 13             // 416/32 k fragments for recurrent mfma
#define NG 5               // col groups (blocks) per (dir,chunk)
#define FPB 20             // col fragments per block
#define FPW 5              // col fragments per wave (4 waves)

typedef _Float16 h16x8 __attribute__((ext_vector_type(8)));
typedef float f32x4 __attribute__((ext_vector_type(4)));
typedef unsigned short us4 __attribute__((ext_vector_type(4)));
typedef unsigned short us8 __attribute__((ext_vector_type(8)));

__device__ inline unsigned short f2h(float f) {
  union { _Float16 h; unsigned short u; } v;
  v.h = (_Float16)f;   // RNE
  return v.u;
}
__device__ inline float h2f(unsigned short s) {
  union { unsigned short u; _Float16 h; } v;
  v.u = s;
  return (float)v.h;
}
__device__ inline float fast_tanh(float x) {
  float x2 = fminf(fmaxf(2.f * x, -30.f), 30.f);
  float e = __expf(x2);
  return (e - 1.f) / (e + 1.f);
}

// ---------------------------------------------------------------------------
// Converters
// ---------------------------------------------------------------------------

// f32 (rows x K) -> fp16 (rows x KP), zero-padded cols [K,KP)
__global__ void conv_x_pad(const float* __restrict__ src,
                           unsigned short* __restrict__ dst,
                           int rows, int K, int KP) {
  long idx = (long)blockIdx.x * 256 + threadIdx.x;
  int kp4 = KP >> 2;
  long total = (long)rows * kp4;
  if (idx >= total) return;
  long m = idx / kp4;
  int c4 = (int)(idx - m * kp4) * 4;
  us4 o;
  if (c4 < K) {
    float4 v = *(const float4*)&src[(size_t)m * K + c4];
    o[0] = f2h(v.x); o[1] = f2h(v.y); o[2] = f2h(v.z); o[3] = f2h(v.w);
  } else {
    o[0] = o[1] = o[2] = o[3] = 0;
  }
  *(us4*)&dst[(size_t)m * KP + c4] = o;
}

// Build GEMM B matrix: row n in [0,3200) = (dir, c), c = 4*u + g (interleaved),
// from w_ih_dir original row (c&3)*HH + (c>>2), K cols padded to KP.
__global__ void conv_wih(const float* __restrict__ wf,
                         const float* __restrict__ wb_,
                         unsigned short* __restrict__ dst, int K, int KP) {
  long idx = (long)blockIdx.x * 256 + threadIdx.x;
  int kp4 = KP >> 2;
  long total = (long)NGEMM * kp4;
  if (idx >= total) return;
  int n = (int)(idx / kp4);
  int c4 = (int)(idx % kp4) * 4;
  int dir = (n >= 1600) ? 1 : 0;
  int c = n - dir * 1600;
  const float* w = dir ? wb_ : wf;
  int orig = (c & 3) * HH + (c >> 2);
  us4 o;
  if (c4 < K) {
    float4 v = *(const float4*)&w[(size_t)orig * K + c4];
    o[0] = f2h(v.x); o[1] = f2h(v.y); o[2] = f2h(v.z); o[3] = f2h(v.w);
  } else {
    o[0] = o[1] = o[2] = o[3] = 0;
  }
  *(us4*)&dst[(size_t)n * KP + c4] = o;
}

// Recurrent weight fragments: dst[(dir*100+fg)*13 + kk][lane*8 .. +8) =
// w_hh_dir[orig(c)][k], c = fg*16 + (lane&15), k = kk*32 + (lane>>4)*8 + e.
__global__ void conv_whh(const float* __restrict__ wf,
                         const float* __restrict__ wb_,
                         unsigned short* __restrict__ dst) {
  int idx = blockIdx.x * 256 + threadIdx.x;
  if (idx >= 2 * NFRAG * KFH * 64) return;
  int l = idx & 63;
  int kk = (idx >> 6) % KFH;
  int fg = (idx / (64 * KFH)) % NFRAG;
  int dir = idx / (64 * KFH * NFRAG);
  const float* w = dir ? wb_ : wf;
  int c = fg * 16 + (l & 15);
  int orig = (c & 3) * HH + (c >> 2);
  int k0 = kk * 32 + (l >> 4) * 8;
  us8 o;
  if (k0 + 7 < HH) {
    float4 a = *(const float4*)&w[(size_t)orig * HH + k0];
    float4 b = *(const float4*)&w[(size_t)orig * HH + k0 + 4];
    o[0] = f2h(a.x); o[1] = f2h(a.y); o[2] = f2h(a.z); o[3] = f2h(a.w);
    o[4] = f2h(b.x); o[5] = f2h(b.y); o[6] = f2h(b.z); o[7] = f2h(b.w);
  } else {
    for (int e = 0; e < 8; ++e) o[e] = 0;
  }
  *(us8*)&dst[(size_t)idx * 8] = o;
}

__global__ void conv_bias(const float* __restrict__ bif, const float* __restrict__ bhf,
                          const float* __restrict__ bib, const float* __restrict__ bhb,
                          float* __restrict__ dst) {
  int n = blockIdx.x * 256 + threadIdx.x;
  if (n >= NGEMM) return;
  int dir = (n >= 1600) ? 1 : 0;
  int c = n - dir * 1600;
  int orig = (c & 3) * HH + (c >> 2);
  dst[n] = dir ? (bib[orig] + bhb[orig]) : (bif[orig] + bhf[orig]);
}

__global__ void zero_flags(int* __restrict__ f) {
  int i = threadIdx.x;
  if (i < 2 * 8 * NG) f[i] = 0;
}

// ---------------------------------------------------------------------------
// GEMM: C[M,N](fp16) = A[M,KP](fp16) * B[N,KP](fp16)^T + bias[N]
// 128x128 tile, BK=64, 4 waves, T2 XOR-swizzled LDS (16B units, ^ (row&7)).
// ---------------------------------------------------------------------------
__global__ __launch_bounds__(256) void gemm_xg(
    const unsigned short* __restrict__ A,
    const unsigned short* __restrict__ Bw,
    const float* __restrict__ bias,
    unsigned short* __restrict__ C, int KP, int N) {
  __shared__ unsigned short As[128 * 64];
  __shared__ unsigned short Bs[128 * 64];
  const int tid = threadIdx.x;
  const int lane = tid & 63, wid = tid >> 6;
  const int wr = wid >> 1, wc = wid & 1;
  const long tM = (long)blockIdx.y * 128;
  const long tN = (long)blockIdx.x * 128;

  f32x4 acc[4][4] = {};

  const int srow = tid >> 3;   // 0..31
  const int su = tid & 7;      // 16B unit within 64-col row

  for (int k0 = 0; k0 < KP; k0 += 64) {
    h16x8 va[4], vb[4];
#pragma unroll
    for (int it = 0; it < 4; ++it) {
      int row = it * 32 + srow;
      va[it] = *(const h16x8*)&A[(tM + row) * KP + k0 + su * 8];
      vb[it] = *(const h16x8*)&Bw[(tN + row) * KP + k0 + su * 8];
    }
    __syncthreads();   // previous iter's LDS reads done
#pragma unroll
    for (int it = 0; it < 4; ++it) {
      int row = it * 32 + srow;
      int us_ = su ^ (row & 7);
      *(h16x8*)&As[row * 64 + us_ * 8] = va[it];
      *(h16x8*)&Bs[row * 64 + us_ * 8] = vb[it];
    }
    __syncthreads();   // staging visible
#pragma unroll
    for (int kk = 0; kk < 2; ++kk) {
      h16x8 afr[4], bfr[4];
      const int uu = (kk * 4 + (lane >> 4)) ^ (lane & 7);  // row&7 == lane&7
#pragma unroll
      for (int m = 0; m < 4; ++m)
        afr[m] = *(const h16x8*)&As[(wr * 64 + m * 16 + (lane & 15)) * 64 + uu * 8];
#pragma unroll
      for (int n = 0; n < 4; ++n)
        bfr[n] = *(const h16x8*)&Bs[(wc * 64 + n * 16 + (lane & 15)) * 64 + uu * 8];
#pragma unroll
      for (int m = 0; m < 4; ++m)
#pragma unroll
        for (int n = 0; n < 4; ++n)
          acc[m][n] = __builtin_amdgcn_mfma_f32_16x16x32_f16(afr[m], bfr[n], acc[m][n], 0, 0, 0);
    }
  }

  const int cr0 = (lane >> 4) * 4;
  const int ccol = lane & 15;
#pragma unroll
  for (int n = 0; n < 4; ++n) {
    long col = tN + wc * 64 + n * 16 + ccol;
    float bv = bias[col];
#pragma unroll
    for (int m = 0; m < 4; ++m) {
      long row = tM + wr * 64 + m * 16 + cr0;
#pragma unroll
      for (int j = 0; j < 4; ++j)
        C[(row + j) * N + col] = f2h(acc[m][n][j] + bv);
    }
  }
}

// ---------------------------------------------------------------------------
// Recurrence. grid = 80 blocks x 256 threads (4 waves, <=512 VGPR/wave).
// blk = dir*40 + chunk*5 + g. Block owns col fragments [g*20, g*20+20);
// wave w owns frags g*20 + w*5 + i. Step s in [1,Lc]: read h(s-1) from
// hbuf[(s-1)&1] (all 400 units, written by the 5-group), mfma vs register
// weights, gates, write own 80-unit h slice to hbuf[s&1] (agent atomics),
// release flag=s. Peers poll flags >= s-1 before reading.
// ---------------------------------------------------------------------------
__global__ __launch_bounds__(256, 1) void lstm_dir(
    const unsigned short* __restrict__ xg,     // MM x NGEMM fp16
    const unsigned short* __restrict__ wprep,  // [2][100][13][512] fp16
    const int* __restrict__ lens,
    float* __restrict__ out,                   // TT x BB x 800 f32
    unsigned* __restrict__ hbuf,               // [2][8][2][16][208] u32
    int* __restrict__ flags) {                 // [2][8][NG]
  const int blk = blockIdx.x;
  const int g = blk % NG;
  const int chunk = (blk / NG) & 7;
  const int dir = blk / (NG * 8);
  const int b0 = chunk * 16;
  const int tid = threadIdx.x;
  const int lane = tid & 63, wid = tid >> 6;
  const int fg0 = g * FPB + wid * FPW;

  h16x8 wb[FPW][KFH];
#pragma unroll
  for (int i = 0; i < FPW; ++i)
#pragma unroll
    for (int kk = 0; kk < KFH; ++kk)
      wb[i][kk] = *(const h16x8*)
          &wprep[(((size_t)(dir * NFRAG + fg0 + i) * KFH + kk) << 9) + lane * 8];

  const int rA = lane & 15;                       // A-frag row (batch)
  const int r2 = ((lane >> 4) << 2) | (lane & 3); // post-transpose batch row
  const int ug = (lane >> 2) & 3;                 // unit-within-fragment
  const int len2 = lens[b0 + r2];
  const int Lc = lens[b0];                        // sorted desc -> chunk max
  const int dcol = dir * 400;
  unsigned* hb = hbuf + (size_t)(dir * 8 + chunk) * 2 * 3328;
  int* flg = flags + (dir * 8 + chunk) * NG;

  float cst[FPW];
#pragma unroll
  for (int i = 0; i < FPW; ++i) cst[i] = 0.f;

  for (int s = 1; s <= Lc; ++s) {
    const int t = dir ? (Lc - s) : (s - 1);
    const size_t xbase = (size_t)(t * BB + b0) * NGEMM + dir * 1600;

    // issue xg loads early (overlap with flag wait)
    f32x4 acc[FPW];
#pragma unroll
    for (int i = 0; i < FPW; ++i) {
      const int col = (fg0 + i) * 16 + (lane & 15);
#pragma unroll
      for (int j = 0; j < 4; ++j)
        acc[i][j] = h2f(xg[xbase + (size_t)((lane >> 4) * 4 + j) * NGEMM + col]);
    }

    h16x8 af[KFH];
    if (s > 1) {
      if (tid < NG) {
        while (__hip_atomic_load(&flg[tid], __ATOMIC_RELAXED,
                                 __HIP_MEMORY_SCOPE_AGENT) < s - 1)
          __builtin_amdgcn_s_sleep(1);
      }
      __syncthreads();
      __builtin_amdgcn_fence(__ATOMIC_ACQUIRE, "agent");
      const unsigned* src = hb + ((s - 1) & 1) * 3328;
#pragma unroll
      for (int kk = 0; kk < KFH; ++kk)
        af[kk] = *(const h16x8*)&src[rA * 208 + kk * 16 + (lane >> 4) * 4];
    } else {
      const h16x8 zf = {0, 0, 0, 0, 0, 0, 0, 0};
#pragma unroll
      for (int kk = 0; kk < KFH; ++kk) af[kk] = zf;
    }

#pragma unroll
    for (int i = 0; i < FPW; ++i)
#pragma unroll
      for (int kk = 0; kk < KFH; ++kk)
        acc[i] = __builtin_amdgcn_mfma_f32_16x16x32_f16(af[kk], wb[i][kk], acc[i], 0, 0, 0);

    unsigned* dst = hb + (s & 1) * 3328;
    const bool mk = (t < len2);
#pragma unroll
    for (int i = 0; i < FPW; ++i) {
      float v0 = acc[i][0], v1 = acc[i][1], v2 = acc[i][2], v3 = acc[i][3];
      // 4x4 transpose within 4-lane groups: (lane p, reg j) -> (lane j, reg p)
      float x = (lane & 1) ? v0 : v1; x = __shfl_xor(x, 1);
      v0 = (lane & 1) ? x : v0; v1 = (lane & 1) ? v1 : x;
      float y = (lane & 1) ? v2 : v3; y = __shfl_xor(y, 1);
      v2 = (lane & 1) ? y : v2; v3 = (lane & 1) ? v3 : y;
      x = (lane & 2) ? v0 : v2; x = __shfl_xor(x, 2);
      v0 = (lane & 2) ? x : v0; v2 = (lane & 2) ? v2 : x;
      y = (lane & 2) ? v1 : v3; y = __shfl_xor(y, 2);
      v1 = (lane & 2) ? y : v1; v3 = (lane & 2) ? v3 : y;
      // v0=i, v1=f, v2=g~, v3=o for (batch row r2, unit u)
      const int fg = fg0 + i;
      const int u = fg * 4 + ug;
      float si = 1.f / (1.f + __expf(-v0));
      float sf = 1.f / (1.f + __expf(-v1));
      float so = 1.f / (1.f + __expf(-v3));
      float c = sf * cst[i] + si * fast_tanh(v2);
      float h = so * fast_tanh(c);
      h = mk ? h : 0.f;
      cst[i] = mk ? c : 0.f;
      out[(size_t)(t * BB + b0 + r2) * 800 + dcol + u] = h;
      unsigned hv = f2h(h);
      unsigned pv = (unsigned)__shfl_xor((int)hv, 4);  // partner unit u^1
      if (!(ug & 1))
        __hip_atomic_store(&dst[r2 * 208 + fg * 2 + (ug >> 1)], hv | (pv << 16),
                           __ATOMIC_RELAXED, __HIP_MEMORY_SCOPE_AGENT);
    }
    __syncthreads();   // all waves' slice stores issued+drained (barrier waits vmcnt)
    if (tid == 0)
      __hip_atomic_store(&flg[g], s, __ATOMIC_RELEASE, __HIP_MEMORY_SCOPE_AGENT);
  }

  // zero-fill t in [len[r], TT) for this chunk's rows, this block's 80 cols
  for (int r = 0; r < 16; ++r) {
    const int l0 = lens[b0 + r];
    const int cnt = (TT - l0) * 20;
    for (int i = tid; i < cnt; i += 256) {
      int tt = l0 + i / 20;
      int c4 = (i % 20) * 4;
      float4 z = {0.f, 0.f, 0.f, 0.f};
      *(float4*)&out[(size_t)(tt * BB + b0 + r) * 800 + dcol + g * 80 + c4] = z;
    }
  }
}

// ---------------------------------------------------------------------------
extern "C" void kernel_launch(void* const* d_in, const int* in_sizes, int n_in,
                              void* d_out, int out_size, void* d_ws, size_t ws_size,
                              hipStream_t stream) {
  const float* x = (const float*)d_in[0];
  const int* lens = (const int*)d_in[1];
  const float* wih[2][2] = {{(const float*)d_in[2], (const float*)d_in[6]},
                            {(const float*)d_in[10], (const float*)d_in[14]}};
  const float* whh[2][2] = {{(const float*)d_in[3], (const float*)d_in[7]},
                            {(const float*)d_in[11], (const float*)d_in[15]}};
  const float* bih[2][2] = {{(const float*)d_in[4], (const float*)d_in[8]},
                            {(const float*)d_in[12], (const float*)d_in[16]}};
  const float* bhh[2][2] = {{(const float*)d_in[5], (const float*)d_in[9]},
                            {(const float*)d_in[13], (const float*)d_in[17]}};
  float* out = (float*)d_out;

  char* ws = (char*)d_ws;
  unsigned short* XG = (unsigned short*)ws;    ws += (size_t)MM * NGEMM * 2;      // 419.4 MB
  unsigned short* XBF = (unsigned short*)ws;   ws += (size_t)MM * KP1 * 2;        // 109.1 MB
  unsigned short* WIH0 = (unsigned short*)ws;  ws += (size_t)NGEMM * KP0 * 2;
  unsigned short* WIH1 = (unsigned short*)ws;  ws += (size_t)NGEMM * KP1 * 2;
  unsigned short* WHH0 = (unsigned short*)ws;  ws += (size_t)2 * NFRAG * KFH * 512 * 2;
  unsigned short* WHH1 = (unsigned short*)ws;  ws += (size_t)2 * NFRAG * KFH * 512 * 2;
  float* BIAS0 = (float*)ws;                   ws += (size_t)NGEMM * 4;
  float* BIAS1 = (float*)ws;                   ws += (size_t)NGEMM * 4;
  unsigned* HBUF = (unsigned*)ws;              ws += (size_t)16 * 2 * 3328 * 4;   // 426 KB
  int* FLAGS = (int*)ws;

  // ---- layer 0 ----
  conv_x_pad<<<(MM * (KP0 / 4) + 255) / 256, 256, 0, stream>>>(x, XBF, MM, DIN, KP0);
  conv_wih<<<(NGEMM * (KP0 / 4) + 255) / 256, 256, 0, stream>>>(wih[0][0], wih[0][1], WIH0, DIN, KP0);
  conv_whh<<<(2 * NFRAG * KFH * 64 + 255) / 256, 256, 0, stream>>>(whh[0][0], whh[0][1], WHH0);
  conv_bias<<<(NGEMM + 255) / 256, 256, 0, stream>>>(bih[0][0], bhh[0][0], bih[0][1], bhh[0][1], BIAS0);
  gemm_xg<<<dim3(NGEMM / 128, MM / 128), 256, 0, stream>>>(XBF, WIH0, BIAS0, XG, KP0, NGEMM);
  zero_flags<<<1, 128, 0, stream>>>(FLAGS);
  lstm_dir<<<80, 256, 0, stream>>>(XG, WHH0, lens, out, HBUF, FLAGS);

  // ---- layer 1 ----
  conv_x_pad<<<(MM * (KP1 / 4) + 255) / 256, 256, 0, stream>>>(out, XBF, MM, 2 * HH, KP1);
  conv_wih<<<(NGEMM * (KP1 / 4) + 255) / 256, 256, 0, stream>>>(wih[1][0], wih[1][1], WIH1, 2 * HH, KP1);
  conv_whh<<<(2 * NFRAG * KFH * 64 + 255) / 256, 256, 0, stream>>>(whh[1][0], whh[1][1], WHH1);
  conv_bias<<<(NGEMM + 255) / 256, 256, 0, stream>>>(bih[1][0], bhh[1][0], bih[1][1], bhh[1][1], BIAS1);
  gemm_xg<<<dim3(NGEMM / 128, MM / 128), 256, 0, stream>>>(XBF, WIH1, BIAS1, XG, KP1, NGEMM);
  zero_flags<<<1, 128, 0, stream>>>(FLAGS);
  lstm_dir<<<80, 256, 0, stream>>>(XG, WHH1, lens, out, HBUF, FLAGS);
}